// Round 1
// baseline (572.952 us; speedup 1.0000x reference)
//
#include <hip/hip_runtime.h>
#include <stdint.h>

#define B_ 4
#define T_ 8192
#define C_ 1024
#define BT_ (B_*T_)
#define NSEG 64
#define SLEN (T_/NSEG)
#define EPS_ 1e-5f

typedef __attribute__((ext_vector_type(8))) short short8;
typedef __attribute__((ext_vector_type(4))) float float4v;
typedef __attribute__((ext_vector_type(4))) unsigned short ushort4v;
typedef unsigned short u16;

__device__ __forceinline__ u16 f2bf(float f){
  union { float f; uint32_t u; } v; v.f = f;
  uint32_t r = v.u + 0x7FFFu + ((v.u >> 16) & 1u);   // round-to-nearest-even
  return (u16)(r >> 16);
}
__device__ __forceinline__ float bf2f(u16 h){
  union { uint32_t u; float f; } v; v.u = ((uint32_t)h) << 16;
  return v.f;
}
// async global->LDS, 16B per lane; LDS dest must be wave-uniform (HW: base + lane*16)
__device__ __forceinline__ void gload16(const void* g, void* l){
  __builtin_amdgcn_global_load_lds((__attribute__((address_space(1))) void*)(void*)g,
                                   (__attribute__((address_space(3))) void*)l,
                                   16, 0, 0);
}

// ---------------- weight cast fp32 -> bf16 (1M elements, grid 1024x256) ----------
__global__ void castw_kernel(const float* __restrict__ in, u16* __restrict__ out){
  int i = blockIdx.x*blockDim.x + threadIdx.x;
  float4v v = ((const float4v*)in)[i];
  ushort4v o;
  o.x=f2bf(v.x); o.y=f2bf(v.y); o.z=f2bf(v.z); o.w=f2bf(v.w);
  ((ushort4v*)out)[i] = o;
}

// ---------------- LayerNorm: one block per row, writes bf16 ----------------------
__global__ __launch_bounds__(256) void ln_kernel(const float* __restrict__ x,
    const float* __restrict__ lw, const float* __restrict__ lb, u16* __restrict__ xxb)
{
  int row = blockIdx.x;
  int tid = threadIdx.x;
  float4v v = ((const float4v*)(x + (size_t)row*C_))[tid];
  float s1 = v.x+v.y+v.z+v.w;
  float s2 = v.x*v.x+v.y*v.y+v.z*v.z+v.w*v.w;
  #pragma unroll
  for (int off=32; off>0; off>>=1){
    s1 += __shfl_down(s1, off, 64);
    s2 += __shfl_down(s2, off, 64);
  }
  __shared__ float red1[4], red2[4];
  if ((tid&63)==0){ red1[tid>>6]=s1; red2[tid>>6]=s2; }
  __syncthreads();
  s1 = red1[0]+red1[1]+red1[2]+red1[3];
  s2 = red2[0]+red2[1]+red2[2]+red2[3];
  float mu = s1*(1.0f/C_);
  float rs = rsqrtf(s2*(1.0f/C_) - mu*mu + EPS_);
  float4v wv = ((const float4v*)lw)[tid];
  float4v bv = ((const float4v*)lb)[tid];
  ushort4v o;
  o.x = f2bf((v.x-mu)*rs*wv.x + bv.x);
  o.y = f2bf((v.y-mu)*rs*wv.y + bv.y);
  o.z = f2bf((v.z-mu)*rs*wv.z + bv.z);
  o.w = f2bf((v.w-mu)*rs*wv.w + bv.w);
  ((ushort4v*)(xxb + (size_t)row*C_))[tid] = o;
}

// ---------------- bf16 GEMM, C = A(MxK) * B(NxK)^T, m97 structure ----------------
// 128x128 tile, BK=32, 4 waves (2x2 of 64x64), mfma_f32_16x16x32_bf16
template<bool F32OUT>
__global__ __launch_bounds__(256) void gemm_bt(const u16* __restrict__ A,
                                               const u16* __restrict__ Bw,
                                               void* __restrict__ Cp)
{
  constexpr int K = C_, N = C_;
  __shared__ __align__(16) u16 As[128*32];
  __shared__ __align__(16) u16 Bs[128*32];
  const int tid  = threadIdx.x;
  const int lane = tid & 63;
  const int wid  = tid >> 6;
  const int wr = wid >> 1, wc = wid & 1;   // wave 2x2 -> 64x64 each
  const int bm = blockIdx.x, bn = blockIdx.y;

  float4v acc[4][4];
  float4v zero = {0.f, 0.f, 0.f, 0.f};
  #pragma unroll
  for (int i=0;i<4;++i)
    #pragma unroll
    for (int j=0;j<4;++j) acc[i][j] = zero;

  const char* Abase = (const char*)(A + (size_t)bm*128*K);
  const char* Bbase = (const char*)(Bw + (size_t)bn*128*K);

  for (int k0 = 0; k0 < K; k0 += 32){
    __syncthreads();                      // previous compute done before overwrite
    // stage 8KB A + 8KB B; per wave: 2 chunks of 1KB each, per lane 16B
    #pragma unroll
    for (int j=0;j<2;++j){
      const int chunk = wid*2 + j;                 // 0..7
      const int rowT  = chunk*16 + (lane>>2);      // tile row 0..127
      const int kb    = (lane&3)*16;               // byte within 64B row-slice
      gload16(Abase + (size_t)rowT*(K*2) + (size_t)k0*2 + kb, (char*)As + chunk*1024);
      gload16(Bbase + (size_t)rowT*(K*2) + (size_t)k0*2 + kb, (char*)Bs + chunk*1024);
    }
    __syncthreads();                      // staged data visible (vmcnt drained)

    short8 afr[4], bfr[4];
    #pragma unroll
    for (int mi=0;mi<4;++mi)
      afr[mi] = *(const short8*)(As + (size_t)(wr*64 + mi*16 + (lane&15))*32 + (lane>>4)*8);
    #pragma unroll
    for (int ni=0;ni<4;++ni)
      bfr[ni] = *(const short8*)(Bs + (size_t)(wc*64 + ni*16 + (lane&15))*32 + (lane>>4)*8);
    #pragma unroll
    for (int mi=0;mi<4;++mi)
      #pragma unroll
      for (int ni=0;ni<4;++ni)
        acc[mi][ni] = __builtin_amdgcn_mfma_f32_16x16x32_bf16(afr[mi], bfr[ni], acc[mi][ni], 0, 0, 0);
  }

  // epilogue: D col = lane&15, row = (lane>>4)*4 + reg  [m89/m91 verified]
  const int cl = lane & 15, rq = lane >> 4;
  const size_t r0 = (size_t)bm*128 + wr*64;
  const int    c0 = bn*128 + wc*64;
  #pragma unroll
  for (int mi=0;mi<4;++mi)
    #pragma unroll
    for (int ni=0;ni<4;++ni)
      #pragma unroll
      for (int j=0;j<4;++j){
        size_t rr = r0 + mi*16 + rq*4 + j;
        int    cc = c0 + ni*16 + cl;
        if constexpr (F32OUT) ((float*)Cp)[rr*N + cc] = acc[mi][ni][j];
        else                  ((u16*)Cp)[rr*N + cc]   = f2bf(acc[mi][ni][j]);
      }
}

// ---------------- WKV segmented scan -------------------------------------------
// pass1: per-segment sums of kv[t] = k*v*exp(td*t)
__global__ __launch_bounds__(256) void wkv_pass1(const u16* __restrict__ kb,
    const u16* __restrict__ vb, const float* __restrict__ tdecay,
    float* __restrict__ segsum)
{
  int c   = blockIdx.x*256 + threadIdx.x;
  int seg = blockIdx.y, b = blockIdx.z;
  float td = -expf(tdecay[c]);
  float d  = expf(td);
  int t0   = seg*SLEN;
  float w  = expf(td * (float)t0);
  size_t base = ((size_t)b*T_ + t0)*C_ + c;
  float s = 0.f;
  for (int i=0;i<SLEN;++i){
    float kk = bf2f(kb[base + (size_t)i*C_]);
    float vv = bf2f(vb[base + (size_t)i*C_]);
    s += kk*vv*w;
    w *= d;
  }
  segsum[((size_t)b*NSEG + seg)*C_ + c] = s;
}

// pass2: exclusive scan of segment sums along seg (tiny)
__global__ void wkv_pass2(const float* __restrict__ segsum, float* __restrict__ segoff){
  int idx = blockIdx.x*256 + threadIdx.x;   // over B_*C_
  int b = idx / C_, c = idx % C_;
  float run = 0.f;
  for (int s=0;s<NSEG;++s){
    size_t o = ((size_t)b*NSEG + s)*C_ + c;
    segoff[o] = run;
    run += segsum[o];
  }
}

// pass3: out = sigmoid(r) * (hist + k*tf), bf16
__global__ __launch_bounds__(256) void wkv_pass3(const u16* __restrict__ kb,
    const u16* __restrict__ vb, const u16* __restrict__ rb,
    const float* __restrict__ tdecay, const float* __restrict__ tfirst,
    const float* __restrict__ segoff, u16* __restrict__ outb)
{
  int c   = blockIdx.x*256 + threadIdx.x;
  int seg = blockIdx.y, b = blockIdx.z;
  float td = -expf(tdecay[c]);
  float d  = expf(td);
  float tf = expf(tfirst[c]);
  int t0   = seg*SLEN;
  float w  = expf(td * (float)t0);
  float hist = segoff[((size_t)b*NSEG + seg)*C_ + c];
  size_t base = ((size_t)b*T_ + t0)*C_ + c;
  for (int i=0;i<SLEN;++i){
    float kk = bf2f(kb[base + (size_t)i*C_]);
    float vv = bf2f(vb[base + (size_t)i*C_]);
    float rr = bf2f(rb[base + (size_t)i*C_]);
    float wkv = hist + kk*tf;
    float sg  = 1.f/(1.f + expf(-rr));
    outb[base + (size_t)i*C_] = f2bf(sg*wkv);
    hist += kk*vv*w;
    w *= d;
  }
}

// ---------------- launcher ------------------------------------------------------
extern "C" void kernel_launch(void* const* d_in, const int* in_sizes, int n_in,
                              void* d_out, int out_size, void* d_ws, size_t ws_size,
                              hipStream_t stream)
{
  (void)in_sizes; (void)n_in; (void)out_size; (void)ws_size;
  const float* x   = (const float*)d_in[0];
  const float* tdc = (const float*)d_in[1];
  const float* tfc = (const float*)d_in[2];
  const float* Wk  = (const float*)d_in[3];
  const float* Wv  = (const float*)d_in[4];
  const float* Wr  = (const float*)d_in[5];
  const float* Wo  = (const float*)d_in[6];
  const float* lw  = (const float*)d_in[7];
  const float* lb  = (const float*)d_in[8];
  float* out = (float*)d_out;

  char* ws = (char*)d_ws;
  u16* xxb = (u16*)(ws);                            // 67MB (also reused as outb)
  u16* rb  = (u16*)(ws + 67108864);                 // 67MB
  u16* Wkb = (u16*)(ws + 134217728);                // 2MB each
  u16* Wvb = (u16*)(ws + 136314880);
  u16* Wrb = (u16*)(ws + 138412032);
  u16* Wob = (u16*)(ws + 140509184);
  float* segsum = (float*)(ws + 142606336);         // 1MB
  float* segoff = (float*)(ws + 143654912);         // 1MB
  // k and v (bf16) live in d_out; both are dead before the final GEMM writes d_out
  u16* kb = (u16*)d_out;
  u16* vb = kb + (size_t)BT_*C_;                    // second half of d_out
  u16* outb = xxb;

  castw_kernel<<<1024,256,0,stream>>>(Wk, Wkb);
  castw_kernel<<<1024,256,0,stream>>>(Wv, Wvb);
  castw_kernel<<<1024,256,0,stream>>>(Wr, Wrb);
  castw_kernel<<<1024,256,0,stream>>>(Wo, Wob);

  ln_kernel<<<BT_,256,0,stream>>>(x, lw, lb, xxb);

  dim3 gg(BT_/128, C_/128);
  gemm_bt<false><<<gg,256,0,stream>>>(xxb, Wkb, kb);
  gemm_bt<false><<<gg,256,0,stream>>>(xxb, Wvb, vb);
  gemm_bt<false><<<gg,256,0,stream>>>(xxb, Wrb, rb);

  dim3 sg(C_/256, NSEG, B_);
  wkv_pass1<<<sg,256,0,stream>>>(kb, vb, tdc, segsum);
  wkv_pass2<<<16,256,0,stream>>>(segsum, segoff);
  wkv_pass3<<<sg,256,0,stream>>>(kb, vb, rb, tdc, tfc, segoff, outb);

  gemm_bt<true><<<gg,256,0,stream>>>(outb, Wob, out);
}

// Round 2
// 536.354 us; speedup vs baseline: 1.0682x; 1.0682x over previous
//
#include <hip/hip_runtime.h>
#include <stdint.h>

#define B_ 4
#define T_ 8192
#define C_ 1024
#define BT_ (B_*T_)
#define NSEG 64
#define SLEN (T_/NSEG)
#define EPS_ 1e-5f
#define NT_ 32            // K-tiles: 1024/32

typedef __attribute__((ext_vector_type(8))) short short8;
typedef __attribute__((ext_vector_type(4))) float float4v;
typedef __attribute__((ext_vector_type(4))) unsigned short ushort4v;
typedef unsigned short u16;

__device__ __forceinline__ u16 f2bf(float f){
  union { float f; uint32_t u; } v; v.f = f;
  uint32_t r = v.u + 0x7FFFu + ((v.u >> 16) & 1u);   // round-to-nearest-even
  return (u16)(r >> 16);
}
__device__ __forceinline__ float bf2f(u16 h){
  union { uint32_t u; float f; } v; v.u = ((uint32_t)h) << 16;
  return v.f;
}
// async global->LDS, 16B per lane; LDS dest is wave-uniform base + lane*16
__device__ __forceinline__ void gload16(const void* g, void* l){
  __builtin_amdgcn_global_load_lds((__attribute__((address_space(1))) void*)(void*)g,
                                   (__attribute__((address_space(3))) void*)l,
                                   16, 0, 0);
}

// ---------------- weight cast fp32 -> bf16 ----------------
__global__ void castw_kernel(const float* __restrict__ in, u16* __restrict__ out){
  int i = blockIdx.x*blockDim.x + threadIdx.x;
  float4v v = ((const float4v*)in)[i];
  ushort4v o;
  o.x=f2bf(v.x); o.y=f2bf(v.y); o.z=f2bf(v.z); o.w=f2bf(v.w);
  ((ushort4v*)out)[i] = o;
}

// ---------------- LayerNorm: one block per row, writes bf16 ----------------
__global__ __launch_bounds__(256) void ln_kernel(const float* __restrict__ x,
    const float* __restrict__ lw, const float* __restrict__ lb, u16* __restrict__ xxb)
{
  int row = blockIdx.x;
  int tid = threadIdx.x;
  float4v v = ((const float4v*)(x + (size_t)row*C_))[tid];
  float s1 = v.x+v.y+v.z+v.w;
  float s2 = v.x*v.x+v.y*v.y+v.z*v.z+v.w*v.w;
  #pragma unroll
  for (int off=32; off>0; off>>=1){
    s1 += __shfl_down(s1, off, 64);
    s2 += __shfl_down(s2, off, 64);
  }
  __shared__ float red1[4], red2[4];
  if ((tid&63)==0){ red1[tid>>6]=s1; red2[tid>>6]=s2; }
  __syncthreads();
  s1 = red1[0]+red1[1]+red1[2]+red1[3];
  s2 = red2[0]+red2[1]+red2[2]+red2[3];
  float mu = s1*(1.0f/C_);
  float rs = rsqrtf(s2*(1.0f/C_) - mu*mu + EPS_);
  float4v wv = ((const float4v*)lw)[tid];
  float4v bv = ((const float4v*)lb)[tid];
  ushort4v o;
  o.x = f2bf((v.x-mu)*rs*wv.x + bv.x);
  o.y = f2bf((v.y-mu)*rs*wv.y + bv.y);
  o.z = f2bf((v.z-mu)*rs*wv.z + bv.z);
  o.w = f2bf((v.w-mu)*rs*wv.w + bv.w);
  ((ushort4v*)(xxb + (size_t)row*C_))[tid] = o;
}

// ---------------- deep-pipelined bf16 GEMM ----------------
// C = A(Mx1024) * B(Nx1024)^T ; 256x256 tile, BK=32, 3 LDS buffers,
// distance-2 prefetch, counted vmcnt(4), 1 barrier per K-tile.
// 8 waves (2M x 4N), per-wave 128x64, acc[8][4], mfma_f32_16x16x32_bf16.
// LDS granule swizzle: physical granule = logical ^ ((row>>1)&3), applied
// via pre-swizzled GLOBAL source (linear global_load_lds dest) + swizzled read.
// Output routing: bn>>2 selects C0/C1/C2 (each [M][1024]); used for fused k|v|r.
template<bool F32OUT>
__global__ __launch_bounds__(512, 2) void gemm_dp(const u16* __restrict__ A,
    const u16* __restrict__ Bw, void* __restrict__ C0, void* __restrict__ C1,
    void* __restrict__ C2, int chunk)
{
  __shared__ __align__(16) u16 As[3*256*32];   // 48 KB
  __shared__ __align__(16) u16 Bs[3*256*32];   // 48 KB

  const int tid  = threadIdx.x;
  const int lane = tid & 63;
  const int wid  = tid >> 6;          // 0..7
  const int wr   = wid >> 2;          // 0..1  (M)
  const int wc   = wid & 3;           // 0..3  (N)

  // bijective XCD swizzle (nwg % 8 == 0)
  const int lin = blockIdx.x;
  const int wg  = (lin & 7)*chunk + (lin >> 3);
  const int bm  = wg & 127;           // 128 M-tiles
  const int bn  = wg >> 7;

  const char* Ab = (const char*)(A  + (size_t)bm*256*C_);
  const char* Bb = (const char*)(Bw + (size_t)bn*256*C_);

  // staging source precompute: thread loads rows j*128 + wid*16 + (lane>>2),
  // k-granule (lane&3) ^ ((lane>>3)&3)  [inverse swizzle]
  const int grow0 = wid*16 + (lane>>2);
  const int gsrc  = (((lane&3) ^ ((lane>>3)&3)) << 4);
  const char* Abt = Ab + (size_t)grow0*2048 + gsrc;
  const char* Bbt = Bb + (size_t)grow0*2048 + gsrc;
  char* AsW = (char*)As + wid*1024;   // wave-uniform LDS dest base
  char* BsW = (char*)Bs + wid*1024;

  // read-side swizzled granule (lane-dependent only)
  const int gph   = ((lane>>4) ^ ((lane>>1)&3)) & 3;
  const int aoffb = (wr*128 + (lane&15))*64 + gph*16;   // byte offset in A buf
  const int boffb = (wc*64  + (lane&15))*64 + gph*16;   // byte offset in B buf

  float4v acc[8][4];
  float4v zero = {0.f,0.f,0.f,0.f};
  #pragma unroll
  for (int i=0;i<8;++i)
    #pragma unroll
    for (int j=0;j<4;++j) acc[i][j]=zero;

  // prologue: stage tiles 0 -> buf0, 1 -> buf1   (4 loads each per thread)
  #pragma unroll
  for (int j=0;j<2;++j){
    gload16(Abt + (size_t)j*262144 + 0*64, AsW + 0*16384 + j*8192);
    gload16(Bbt + (size_t)j*262144 + 0*64, BsW + 0*16384 + j*8192);
  }
  #pragma unroll
  for (int j=0;j<2;++j){
    gload16(Abt + (size_t)j*262144 + 1*64, AsW + 1*16384 + j*8192);
    gload16(Bbt + (size_t)j*262144 + 1*64, BsW + 1*16384 + j*8192);
  }

  int rd = 0, st = 2;
  for (int kt=0; kt<NT_; ++kt){
    // wait: all loads except (possibly) next tile's 4 have retired
    if (kt < NT_-1) { asm volatile("s_waitcnt vmcnt(4)" ::: "memory"); }
    else            { asm volatile("s_waitcnt vmcnt(0)" ::: "memory"); }
    __builtin_amdgcn_sched_barrier(0);
    __builtin_amdgcn_s_barrier();
    __builtin_amdgcn_sched_barrier(0);

    // prefetch tile kt+2 into buffer st (its old contents finished at kt-1)
    if (kt+2 < NT_){
      #pragma unroll
      for (int j=0;j<2;++j){
        gload16(Abt + (size_t)j*262144 + (size_t)(kt+2)*64, AsW + st*16384 + j*8192);
        gload16(Bbt + (size_t)j*262144 + (size_t)(kt+2)*64, BsW + st*16384 + j*8192);
      }
    }

    const char* Abuf = (const char*)As + rd*16384;
    const char* Bbuf = (const char*)Bs + rd*16384;
    short8 bfr[4];
    #pragma unroll
    for (int ni=0;ni<4;++ni)
      bfr[ni] = *(const short8*)(Bbuf + boffb + ni*1024);
    __builtin_amdgcn_s_setprio(1);
    #pragma unroll
    for (int mi=0;mi<8;++mi){
      short8 a = *(const short8*)(Abuf + aoffb + mi*1024);
      #pragma unroll
      for (int ni=0;ni<4;++ni)
        acc[mi][ni] = __builtin_amdgcn_mfma_f32_16x16x32_bf16(a, bfr[ni], acc[mi][ni], 0,0,0);
    }
    __builtin_amdgcn_s_setprio(0);
    // all frag ds_reads complete before next barrier (stage-write safety)
    asm volatile("s_waitcnt lgkmcnt(0)" ::: "memory");
    __builtin_amdgcn_sched_barrier(0);

    rd = (rd==2)?0:rd+1;
    st = (st==2)?0:st+1;
  }

  // epilogue: D col = lane&15, row = (lane>>4)*4 + j
  const int cl = lane & 15, rq = lane >> 4;
  const size_t rbase = (size_t)bm*256 + wr*128;
  const int sel = bn >> 2;
  const int c0 = (bn&3)*256 + wc*64;
  void* cb = (sel==0) ? C0 : ((sel==1) ? C1 : C2);
  #pragma unroll
  for (int mi=0;mi<8;++mi)
    #pragma unroll
    for (int ni=0;ni<4;++ni)
      #pragma unroll
      for (int j=0;j<4;++j){
        size_t rr = rbase + mi*16 + rq*4 + j;
        int    cc = c0 + ni*16 + cl;
        if constexpr (F32OUT) ((float*)cb)[rr*1024 + cc] = acc[mi][ni][j];
        else                  ((u16*)cb)[rr*1024 + cc]   = f2bf(acc[mi][ni][j]);
      }
}

// ---------------- WKV segmented scan ----------------
__global__ __launch_bounds__(256) void wkv_pass1(const u16* __restrict__ kb,
    const u16* __restrict__ vb, const float* __restrict__ tdecay,
    float* __restrict__ segsum)
{
  int c   = blockIdx.x*256 + threadIdx.x;
  int seg = blockIdx.y, b = blockIdx.z;
  float td = -expf(tdecay[c]);
  float d  = expf(td);
  int t0   = seg*SLEN;
  float w  = expf(td * (float)t0);
  size_t base = ((size_t)b*T_ + t0)*C_ + c;
  float s = 0.f;
  for (int i=0;i<SLEN;++i){
    float kk = bf2f(kb[base + (size_t)i*C_]);
    float vv = bf2f(vb[base + (size_t)i*C_]);
    s += kk*vv*w;
    w *= d;
  }
  segsum[((size_t)b*NSEG + seg)*C_ + c] = s;
}

__global__ void wkv_pass2(const float* __restrict__ segsum, float* __restrict__ segoff){
  int idx = blockIdx.x*256 + threadIdx.x;   // over B_*C_
  int b = idx / C_, c = idx % C_;
  float run = 0.f;
  for (int s=0;s<NSEG;++s){
    size_t o = ((size_t)b*NSEG + s)*C_ + c;
    segoff[o] = run;
    run += segsum[o];
  }
}

__global__ __launch_bounds__(256) void wkv_pass3(const u16* __restrict__ kb,
    const u16* __restrict__ vb, const u16* __restrict__ rb,
    const float* __restrict__ tdecay, const float* __restrict__ tfirst,
    const float* __restrict__ segoff, u16* __restrict__ outb)
{
  int c   = blockIdx.x*256 + threadIdx.x;
  int seg = blockIdx.y, b = blockIdx.z;
  float td = -expf(tdecay[c]);
  float d  = expf(td);
  float tf = expf(tfirst[c]);
  int t0   = seg*SLEN;
  float w  = expf(td * (float)t0);
  float hist = segoff[((size_t)b*NSEG + seg)*C_ + c];
  size_t base = ((size_t)b*T_ + t0)*C_ + c;
  for (int i=0;i<SLEN;++i){
    float kk = bf2f(kb[base + (size_t)i*C_]);
    float vv = bf2f(vb[base + (size_t)i*C_]);
    float rr = bf2f(rb[base + (size_t)i*C_]);
    float wkv = hist + kk*tf;
    float sg  = 1.f/(1.f + expf(-rr));
    outb[base + (size_t)i*C_] = f2bf(sg*wkv);
    hist += kk*vv*w;
    w *= d;
  }
}

// ---------------- launcher ----------------
extern "C" void kernel_launch(void* const* d_in, const int* in_sizes, int n_in,
                              void* d_out, int out_size, void* d_ws, size_t ws_size,
                              hipStream_t stream)
{
  (void)in_sizes; (void)n_in; (void)out_size; (void)ws_size;
  const float* x   = (const float*)d_in[0];
  const float* tdc = (const float*)d_in[1];
  const float* tfc = (const float*)d_in[2];
  const float* Wk  = (const float*)d_in[3];
  const float* Wv  = (const float*)d_in[4];
  const float* Wr  = (const float*)d_in[5];
  const float* Wo  = (const float*)d_in[6];
  const float* lw  = (const float*)d_in[7];
  const float* lb  = (const float*)d_in[8];
  float* out = (float*)d_out;

  char* ws = (char*)d_ws;
  u16* xxb = (u16*)(ws);                            // 67MB (also reused as outb)
  u16* rb  = (u16*)(ws + 67108864);                 // 67MB
  u16* Wkb = (u16*)(ws + 134217728);                // 2MB each; Wk|Wv|Wr contiguous
  u16* Wvb = (u16*)(ws + 136314880);
  u16* Wrb = (u16*)(ws + 138412032);
  u16* Wob = (u16*)(ws + 140509184);
  float* segsum = (float*)(ws + 142606336);         // 1MB
  float* segoff = (float*)(ws + 143654912);         // 1MB
  // k and v (bf16) live in d_out; both are dead before the final GEMM writes d_out
  u16* kb = (u16*)d_out;
  u16* vb = kb + (size_t)BT_*C_;
  u16* outb = xxb;

  castw_kernel<<<1024,256,0,stream>>>(Wk, Wkb);
  castw_kernel<<<1024,256,0,stream>>>(Wv, Wvb);
  castw_kernel<<<1024,256,0,stream>>>(Wr, Wrb);
  castw_kernel<<<1024,256,0,stream>>>(Wo, Wob);

  ln_kernel<<<BT_,256,0,stream>>>(x, lw, lb, xxb);

  // fused k|v|r GEMM: N = 3072 (12 bn-tiles), grid 1536, chunk = 1536/8
  gemm_dp<false><<<1536,512,0,stream>>>(xxb, Wkb, kb, vb, rb, 192);

  dim3 sg(C_/256, NSEG, B_);
  wkv_pass1<<<sg,256,0,stream>>>(kb, vb, tdc, segsum);
  wkv_pass2<<<16,256,0,stream>>>(segsum, segoff);
  wkv_pass3<<<sg,256,0,stream>>>(kb, vb, rb, tdc, tfc, segoff, outb);

  // output GEMM: N = 1024 (4 bn-tiles), grid 512, chunk = 512/8
  gemm_dp<true><<<512,512,0,stream>>>(outb, Wob, out, out, out, 64);
}

// Round 3
// 500.198 us; speedup vs baseline: 1.1454x; 1.0723x over previous
//
#include <hip/hip_runtime.h>
#include <stdint.h>

#define B_ 4
#define T_ 8192
#define C_ 1024
#define BT_ (B_*T_)
#define NSEG 64
#define SLEN (T_/NSEG)
#define EPS_ 1e-5f
#define NT_ 16            // K-tiles: 1024/64

typedef __attribute__((ext_vector_type(8))) short short8;
typedef __attribute__((ext_vector_type(4))) float float4v;
typedef __attribute__((ext_vector_type(4))) unsigned short ushort4v;
typedef unsigned short u16;

__device__ __forceinline__ u16 f2bf(float f){
  union { float f; uint32_t u; } v; v.f = f;
  uint32_t r = v.u + 0x7FFFu + ((v.u >> 16) & 1u);   // round-to-nearest-even
  return (u16)(r >> 16);
}
__device__ __forceinline__ float bf2f(u16 h){
  union { uint32_t u; float f; } v; v.u = ((uint32_t)h) << 16;
  return v.f;
}
__device__ __forceinline__ void gload16(const void* g, void* l){
  __builtin_amdgcn_global_load_lds((__attribute__((address_space(1))) void*)(void*)g,
                                   (__attribute__((address_space(3))) void*)l,
                                   16, 0, 0);
}

// ---------------- weight cast fp32 -> bf16 ----------------
__global__ void castw_kernel(const float* __restrict__ in, u16* __restrict__ out){
  int i = blockIdx.x*blockDim.x + threadIdx.x;
  float4v v = ((const float4v*)in)[i];
  ushort4v o;
  o.x=f2bf(v.x); o.y=f2bf(v.y); o.z=f2bf(v.z); o.w=f2bf(v.w);
  ((ushort4v*)out)[i] = o;
}

// ---------------- LayerNorm ----------------
__global__ __launch_bounds__(256) void ln_kernel(const float* __restrict__ x,
    const float* __restrict__ lw, const float* __restrict__ lb, u16* __restrict__ xxb)
{
  int row = blockIdx.x;
  int tid = threadIdx.x;
  float4v v = ((const float4v*)(x + (size_t)row*C_))[tid];
  float s1 = v.x+v.y+v.z+v.w;
  float s2 = v.x*v.x+v.y*v.y+v.z*v.z+v.w*v.w;
  #pragma unroll
  for (int off=32; off>0; off>>=1){
    s1 += __shfl_down(s1, off, 64);
    s2 += __shfl_down(s2, off, 64);
  }
  __shared__ float red1[4], red2[4];
  if ((tid&63)==0){ red1[tid>>6]=s1; red2[tid>>6]=s2; }
  __syncthreads();
  s1 = red1[0]+red1[1]+red1[2]+red1[3];
  s2 = red2[0]+red2[1]+red2[2]+red2[3];
  float mu = s1*(1.0f/C_);
  float rs = rsqrtf(s2*(1.0f/C_) - mu*mu + EPS_);
  float4v wv = ((const float4v*)lw)[tid];
  float4v bv = ((const float4v*)lb)[tid];
  ushort4v o;
  o.x = f2bf((v.x-mu)*rs*wv.x + bv.x);
  o.y = f2bf((v.y-mu)*rs*wv.y + bv.y);
  o.z = f2bf((v.z-mu)*rs*wv.z + bv.z);
  o.w = f2bf((v.w-mu)*rs*wv.w + bv.w);
  ((ushort4v*)(xxb + (size_t)row*C_))[tid] = o;
}

// ---------------- 8-phase deep-pipelined bf16 GEMM ----------------
// C = A(Mx1024)*B(Nx1024)^T; 256x256 tile, BK=64, 2 LDS buffers (128KB),
// 4 phases/K-tile (quadrant zigzag), stage kt+2 at phase 4, gate vmcnt(8).
// 8 waves (2M x 4N), wave tile 128x64, acc[8][4].
// LDS layout per matrix: [buf][kstep(2)][row(256)][32 elems], granule-XOR swizzle
// phys_granule = logical ^ ((row>>1)&3)  (measured 0 bank conflicts, round 2).
#define SYNC() do{ __builtin_amdgcn_sched_barrier(0); __builtin_amdgcn_s_barrier(); __builtin_amdgcn_sched_barrier(0); }while(0)

#define RD_A(DST, MH, BO) \
  _Pragma("unroll") for (int mt=0; mt<4; ++mt) \
    _Pragma("unroll") for (int ks=0; ks<2; ++ks) \
      DST[mt*2+ks] = *(const short8*)(lds + (BO) + ks*16384 + aoff0 + ((MH)*4+mt)*1024);

#define RD_B(DST, NH, BO) \
  _Pragma("unroll") for (int nt=0; nt<2; ++nt) \
    _Pragma("unroll") for (int ks=0; ks<2; ++ks) \
      DST[nt*2+ks] = *(const short8*)(lds + (BO) + ks*16384 + boff0 + ((NH)*2+nt)*1024);

#define MFMA_Q(AS, BS, MH, NH) do{ \
  __builtin_amdgcn_s_setprio(1); \
  _Pragma("unroll") for (int ks=0; ks<2; ++ks) \
    _Pragma("unroll") for (int mt=0; mt<4; ++mt) \
      _Pragma("unroll") for (int nt=0; nt<2; ++nt) \
        acc[(MH)*4+mt][(NH)*2+nt] = __builtin_amdgcn_mfma_f32_16x16x32_bf16( \
            AS[mt*2+ks], BS[nt*2+ks], acc[(MH)*4+mt][(NH)*2+nt], 0,0,0); \
  __builtin_amdgcn_s_setprio(0); \
}while(0)

template<bool F32OUT>
__global__ __launch_bounds__(512, 2) void gemm_dp(const u16* __restrict__ A,
    const u16* __restrict__ Bw, void* __restrict__ C0, void* __restrict__ C1,
    void* __restrict__ C2, int nbn)
{
  __shared__ __align__(1024) char lds[131072];   // A: [0,64K), B: [64K,128K)

  const int tid  = threadIdx.x;
  const int lane = tid & 63;
  const int wid  = tid >> 6;          // 0..7
  const int wr   = wid >> 2;          // 0..1  (M)
  const int wc   = wid & 3;           // 0..3  (N)

  // XCD mapping: xcd = lin%8 owns 16 consecutive bm; bn fastest inside.
  const int lin = blockIdx.x;
  const int x   = lin & 7;
  const int wl  = lin >> 3;
  const int bm  = x*16 + wl / nbn;
  const int bn  = wl % nbn;

  // ---- read-side addressing (frag reads) ----
  const int l15   = lane & 15;
  const int lswz  = ((lane>>4) ^ ((l15>>1)&3)) << 4;     // conflict-free XOR swizzle
  const int aoff0 = (wr*128 + l15)*64 + lswz;            // A region base 0
  const int boff0 = 65536 + (wc*64 + l15)*64 + lswz;     // B region base 64K

  // ---- staging addressing ----
  const int kk   = wid >> 2;          // kstep plane this wave stages
  const int rg0  = (wid & 3)*2;       // row-group pair
  const int kkL  = kk*16384;
  const char* Asrc = ((const char*)A)  + ((size_t)bm*256 + (lane>>2))*2048
                     + (((lane&3) ^ ((lane>>3)&3)) << 4) + kk*64;
  const char* Bsrc = ((const char*)Bw) + ((size_t)bn*256 + (lane>>2))*2048
                     + (((lane&3) ^ ((lane>>3)&3)) << 4) + kk*64;

  float4v acc[8][4];
  float4v zero = {0.f,0.f,0.f,0.f};
  #pragma unroll
  for (int i=0;i<8;++i)
    #pragma unroll
    for (int j=0;j<4;++j) acc[i][j]=zero;

  // stage one K-tile (8 loads/thread: 2 chunks x {A0,A1,B0,B1})
  auto stage = [&](int bo, int ktB){
    #pragma unroll
    for (int h=0; h<2; ++h)
      #pragma unroll
      for (int q=0; q<2; ++q){
        const int rowoff = h*128 + (rg0+q)*16;
        gload16(Asrc + (size_t)rowoff*2048 + ktB, lds + bo + kkL + rowoff*64);
        gload16(Bsrc + (size_t)rowoff*2048 + ktB, lds + 65536 + bo + kkL + rowoff*64);
      }
  };

  // prologue: kt0 -> buf0, kt1 -> buf1; gate kt0 with 8 in flight
  stage(0, 0);
  stage(32768, 128);
  asm volatile("s_waitcnt vmcnt(8)" ::: "memory");
  SYNC();

  short8 A0r[8], A1r[8], B0r[4], B1r[4];

  #define KTILE(KT, BO) do{ \
    /* ph1: quadrant (0,0) */ \
    RD_A(A0r, 0, BO); RD_B(B0r, 0, BO); \
    SYNC(); \
    MFMA_Q(A0r, B0r, 0, 0); \
    SYNC(); \
    /* ph2: quadrant (1,0) */ \
    RD_A(A1r, 1, BO); \
    SYNC(); \
    MFMA_Q(A1r, B0r, 1, 0); \
    SYNC(); \
    /* ph3: quadrant (1,1) */ \
    RD_B(B1r, 1, BO); \
    SYNC(); \
    MFMA_Q(A1r, B1r, 1, 1); \
    SYNC(); \
    /* ph4: quadrant (0,1) + stage kt+2 + counted gate */ \
    if ((KT) < NT_-2) stage(BO, ((KT)+2)*128); \
    MFMA_Q(A0r, B1r, 0, 1); \
    if ((KT) < NT_-1){ \
      if ((KT) < NT_-2) { asm volatile("s_waitcnt vmcnt(8)" ::: "memory"); } \
      else              { asm volatile("s_waitcnt vmcnt(0)" ::: "memory"); } \
      SYNC(); \
    } \
  }while(0)

  for (int kt2=0; kt2<NT_; kt2+=2){
    KTILE(kt2,   0);
    KTILE(kt2+1, 32768);
  }
  #undef KTILE

  // epilogue: D col = lane&15, row = (lane>>4)*4 + j
  const int cl = l15, rq = lane >> 4;
  const size_t rbase = (size_t)bm*256 + wr*128;
  const int sel = bn >> 2;
  const int c0 = (bn&3)*256 + wc*64;
  void* cb = (sel==0) ? C0 : ((sel==1) ? C1 : C2);
  #pragma unroll
  for (int mi=0;mi<8;++mi)
    #pragma unroll
    for (int ni=0;ni<4;++ni)
      #pragma unroll
      for (int j=0;j<4;++j){
        size_t rr = rbase + mi*16 + rq*4 + j;
        int    cc = c0 + ni*16 + cl;
        if constexpr (F32OUT) ((float*)cb)[rr*1024 + cc] = acc[mi][ni][j];
        else                  ((u16*)cb)[rr*1024 + cc]   = f2bf(acc[mi][ni][j]);
      }
}

// ---------------- WKV segmented scan ----------------
__global__ __launch_bounds__(256) void wkv_pass1(const u16* __restrict__ kb,
    const u16* __restrict__ vb, const float* __restrict__ tdecay,
    float* __restrict__ segsum)
{
  int c   = blockIdx.x*256 + threadIdx.x;
  int seg = blockIdx.y, b = blockIdx.z;
  float td = -expf(tdecay[c]);
  float d  = expf(td);
  int t0   = seg*SLEN;
  float w  = expf(td * (float)t0);
  size_t base = ((size_t)b*T_ + t0)*C_ + c;
  float s = 0.f;
  for (int i=0;i<SLEN;++i){
    float kk = bf2f(kb[base + (size_t)i*C_]);
    float vv = bf2f(vb[base + (size_t)i*C_]);
    s += kk*vv*w;
    w *= d;
  }
  segsum[((size_t)b*NSEG + seg)*C_ + c] = s;
}

__global__ void wkv_pass2(const float* __restrict__ segsum, float* __restrict__ segoff){
  int idx = blockIdx.x*256 + threadIdx.x;   // over B_*C_
  int b = idx / C_, c = idx % C_;
  float run = 0.f;
  for (int s=0;s<NSEG;++s){
    size_t o = ((size_t)b*NSEG + s)*C_ + c;
    segoff[o] = run;
    run += segsum[o];
  }
}

__global__ __launch_bounds__(256) void wkv_pass3(const u16* __restrict__ kb,
    const u16* __restrict__ vb, const u16* __restrict__ rb,
    const float* __restrict__ tdecay, const float* __restrict__ tfirst,
    const float* __restrict__ segoff, u16* __restrict__ outb)
{
  int c   = blockIdx.x*256 + threadIdx.x;
  int seg = blockIdx.y, b = blockIdx.z;
  float td = -expf(tdecay[c]);
  float d  = expf(td);
  float tf = expf(tfirst[c]);
  int t0   = seg*SLEN;
  float w  = expf(td * (float)t0);
  float hist = segoff[((size_t)b*NSEG + seg)*C_ + c];
  size_t base = ((size_t)b*T_ + t0)*C_ + c;
  for (int i=0;i<SLEN;++i){
    float kk = bf2f(kb[base + (size_t)i*C_]);
    float vv = bf2f(vb[base + (size_t)i*C_]);
    float rr = bf2f(rb[base + (size_t)i*C_]);
    float wkv = hist + kk*tf;
    float sg  = 1.f/(1.f + expf(-rr));
    outb[base + (size_t)i*C_] = f2bf(sg*wkv);
    hist += kk*vv*w;
    w *= d;
  }
}

// ---------------- launcher ----------------
extern "C" void kernel_launch(void* const* d_in, const int* in_sizes, int n_in,
                              void* d_out, int out_size, void* d_ws, size_t ws_size,
                              hipStream_t stream)
{
  (void)in_sizes; (void)n_in; (void)out_size; (void)ws_size;
  const float* x   = (const float*)d_in[0];
  const float* tdc = (const float*)d_in[1];
  const float* tfc = (const float*)d_in[2];
  const float* Wk  = (const float*)d_in[3];
  const float* Wv  = (const float*)d_in[4];
  const float* Wr  = (const float*)d_in[5];
  const float* Wo  = (const float*)d_in[6];
  const float* lw  = (const float*)d_in[7];
  const float* lb  = (const float*)d_in[8];
  float* out = (float*)d_out;

  char* ws = (char*)d_ws;
  u16* xxb = (u16*)(ws);                            // 67MB (also reused as outb)
  u16* rb  = (u16*)(ws + 67108864);                 // 67MB
  u16* Wkb = (u16*)(ws + 134217728);                // 2MB each; Wk|Wv|Wr contiguous
  u16* Wvb = (u16*)(ws + 136314880);
  u16* Wrb = (u16*)(ws + 138412032);
  u16* Wob = (u16*)(ws + 140509184);
  float* segsum = (float*)(ws + 142606336);         // 1MB
  float* segoff = (float*)(ws + 143654912);         // 1MB
  u16* kb = (u16*)d_out;                            // k,v live in d_out halves
  u16* vb = kb + (size_t)BT_*C_;
  u16* outb = xxb;

  castw_kernel<<<1024,256,0,stream>>>(Wk, Wkb);
  castw_kernel<<<1024,256,0,stream>>>(Wv, Wvb);
  castw_kernel<<<1024,256,0,stream>>>(Wr, Wrb);
  castw_kernel<<<1024,256,0,stream>>>(Wo, Wob);

  ln_kernel<<<BT_,256,0,stream>>>(x, lw, lb, xxb);

  // fused k|v|r GEMM: N = 3072 (12 bn-tiles), grid 1536
  gemm_dp<false><<<1536,512,0,stream>>>(xxb, Wkb, kb, vb, rb, 12);

  dim3 sg(C_/256, NSEG, B_);
  wkv_pass1<<<sg,256,0,stream>>>(kb, vb, tdc, segsum);
  wkv_pass2<<<16,256,0,stream>>>(segsum, segoff);
  wkv_pass3<<<sg,256,0,stream>>>(kb, vb, rb, tdc, tfc, segoff, outb);

  // output GEMM: N = 1024 (4 bn-tiles), grid 512
  gemm_dp<true><<<512,512,0,stream>>>(outb, Wob, out, out, out, 4);
}